// Round 4
// baseline (4745.358 us; speedup 1.0000x reference)
//
#include <hip/hip_runtime.h>
#include <hip/hip_bf16.h>
#include <math.h>

#define D_MODEL 512
#define N_HEADS 8
#define D_HEAD  64
#define D_FF    2048
#define SEQ     1024
#define BATCHN  4
#define TOKENS  (BATCHN*SEQ)          // 4096
#define H_ELEMS (TOKENS*D_MODEL)      // 2097152
#define ATTN_PER_LAYER (BATCHN*N_HEADS*SEQ*SEQ)  // 33554432

// ---------------------------------------------------------------------------
// Embedding + sinusoidal positional encoding
// ---------------------------------------------------------------------------
__global__ __launch_bounds__(256) void embed_pe_kernel(const int* __restrict__ x,
                                                       const float* __restrict__ emb,
                                                       float* __restrict__ h)
{
    const int tok = blockIdx.x;          // 0..4095
    const int t   = threadIdx.x;         // 0..255 -> handles dims (2t, 2t+1)
    const int s   = tok & (SEQ - 1);
    const int id  = x[tok];
    const float cf = -0.017988946039015968f;   // -ln(10000)/512
    float div = expf((float)(2 * t) * cf);
    float p   = (float)s * div;
    h[(long)tok * D_MODEL + 2 * t]     = emb[id * D_MODEL + 2 * t]     + sinf(p);
    h[(long)tok * D_MODEL + 2 * t + 1] = emb[id * D_MODEL + 2 * t + 1] + cosf(p);
}

// ---------------------------------------------------------------------------
// Generic 64x64 tiled fp32 GEMM, 256 threads, 4x4 micro-tile, BK=32.
// EPI: 0=none, 1=residual add, 2=scores (scale + key-pad mask -> -1e9)
// BT:  B given as [N,K] row-major (used for Q@K^T)
// Batch: blockIdx.z -> zb=z>>3 (batch), zh=z&7 (head); per-operand offsets
//        off = zb*SB + zh*SH  (pure-z stride expressible as SB=8*S, SH=S)
// ---------------------------------------------------------------------------
template<int EPI, bool BT>
__global__ __launch_bounds__(256) void gemm64(
    const float* __restrict__ A, const float* __restrict__ Bm,
    const float* __restrict__ Res, const int* __restrict__ xmask,
    float* __restrict__ C,
    int M, int N, int K, int lda, int ldb, int ldc,
    long aSB, long aSH, long bSB, long bSH, long cSB, long cSH,
    float scale)
{
    __shared__ float As[32][68];
    __shared__ float Bs[32][68];

    const int t  = threadIdx.x;
    const int tx = t & 15, ty = t >> 4;
    const int m0 = blockIdx.y * 64, n0 = blockIdx.x * 64;
    const int zb = blockIdx.z >> 3, zh = blockIdx.z & 7;
    A  += zb * aSB + zh * aSH;
    Bm += zb * bSB + zh * bSH;
    C  += zb * cSB + zh * cSH;

    float acc[4][4] = {};
    const int lr = t >> 2, lq = t & 3;   // transposed loads: row, k-quad-group
    const int bk = t >> 3, bq = t & 7;   // row-major B load

    for (int k0 = 0; k0 < K; k0 += 32) {
        __syncthreads();
        {   // A tile: 64 rows x 32 k, store k-major (transposed)
            const float* gA = A + (long)(m0 + lr) * lda + k0 + lq * 8;
            float4 a0 = *(const float4*)gA;
            float4 a1 = *(const float4*)(gA + 4);
            As[lq*8+0][lr] = a0.x; As[lq*8+1][lr] = a0.y;
            As[lq*8+2][lr] = a0.z; As[lq*8+3][lr] = a0.w;
            As[lq*8+4][lr] = a1.x; As[lq*8+5][lr] = a1.y;
            As[lq*8+6][lr] = a1.z; As[lq*8+7][lr] = a1.w;
        }
        if (!BT) {   // B row-major [K,N]: 32 k-rows x 64 n
            const float* gB = Bm + (long)(k0 + bk) * ldb + n0 + bq * 8;
            *(float4*)&Bs[bk][bq*8]     = *(const float4*)gB;
            *(float4*)&Bs[bk][bq*8 + 4] = *(const float4*)(gB + 4);
        } else {     // B is [N,K] row-major: load like A, store k-major
            const float* gB = Bm + (long)(n0 + lr) * ldb + k0 + lq * 8;
            float4 b0 = *(const float4*)gB;
            float4 b1 = *(const float4*)(gB + 4);
            Bs[lq*8+0][lr] = b0.x; Bs[lq*8+1][lr] = b0.y;
            Bs[lq*8+2][lr] = b0.z; Bs[lq*8+3][lr] = b0.w;
            Bs[lq*8+4][lr] = b1.x; Bs[lq*8+5][lr] = b1.y;
            Bs[lq*8+6][lr] = b1.z; Bs[lq*8+7][lr] = b1.w;
        }
        __syncthreads();
        #pragma unroll
        for (int kk = 0; kk < 32; ++kk) {
            float a[4], b[4];
            *(float4*)a = *(const float4*)&As[kk][ty * 4];
            *(float4*)b = *(const float4*)&Bs[kk][tx * 4];
            #pragma unroll
            for (int i = 0; i < 4; ++i)
                #pragma unroll
                for (int j = 0; j < 4; ++j)
                    acc[i][j] += a[i] * b[j];
        }
    }

    const int* xrow = (EPI == 2) ? (xmask + zb * SEQ) : nullptr;
    #pragma unroll
    for (int i = 0; i < 4; ++i) {
        const long row = m0 + ty * 4 + i;
        alignas(16) float o[4];
        #pragma unroll
        for (int j = 0; j < 4; ++j) {
            const int col = n0 + tx * 4 + j;
            float s = acc[i][j];
            if (EPI == 1) s += Res[row * ldc + col];
            if (EPI == 2) s = (xrow[col] == 0) ? -1e9f : s * scale;
            o[j] = s;
        }
        *(float4*)&C[row * ldc + n0 + tx * 4] = *(const float4*)o;
    }
}

// ---------------------------------------------------------------------------
// 128x128 tiled fp32 GEMM, 256 threads, 8x8 micro-tile, BK=16 (FFN1 + ReLU)
// ---------------------------------------------------------------------------
template<bool RELU>
__global__ __launch_bounds__(256) void gemm128(
    const float* __restrict__ A, const float* __restrict__ Bm,
    float* __restrict__ C, int M, int N, int K, int lda, int ldb, int ldc)
{
    __shared__ float As[16][132];
    __shared__ float Bs[16][132];

    const int t  = threadIdx.x;
    const int tx = t & 15, ty = t >> 4;
    const int m0 = blockIdx.y * 128, n0 = blockIdx.x * 128;

    float acc[8][8] = {};
    const int ar = t >> 1, ah = t & 1;   // A: 128 rows x 16 k
    const int bk = t >> 4, bq = t & 15;  // B: 16 k-rows x 128 n

    for (int k0 = 0; k0 < K; k0 += 16) {
        __syncthreads();
        {
            const float* gA = A + (long)(m0 + ar) * lda + k0 + ah * 8;
            float4 a0 = *(const float4*)gA;
            float4 a1 = *(const float4*)(gA + 4);
            As[ah*8+0][ar] = a0.x; As[ah*8+1][ar] = a0.y;
            As[ah*8+2][ar] = a0.z; As[ah*8+3][ar] = a0.w;
            As[ah*8+4][ar] = a1.x; As[ah*8+5][ar] = a1.y;
            As[ah*8+6][ar] = a1.z; As[ah*8+7][ar] = a1.w;
        }
        {
            const float* gB = Bm + (long)(k0 + bk) * ldb + n0 + bq * 8;
            *(float4*)&Bs[bk][bq*8]     = *(const float4*)gB;
            *(float4*)&Bs[bk][bq*8 + 4] = *(const float4*)(gB + 4);
        }
        __syncthreads();
        #pragma unroll
        for (int kk = 0; kk < 16; ++kk) {
            float a[8], b[8];
            *(float4*)&a[0] = *(const float4*)&As[kk][ty * 8];
            *(float4*)&a[4] = *(const float4*)&As[kk][ty * 8 + 4];
            *(float4*)&b[0] = *(const float4*)&Bs[kk][tx * 8];
            *(float4*)&b[4] = *(const float4*)&Bs[kk][tx * 8 + 4];
            #pragma unroll
            for (int i = 0; i < 8; ++i)
                #pragma unroll
                for (int j = 0; j < 8; ++j)
                    acc[i][j] += a[i] * b[j];
        }
    }

    #pragma unroll
    for (int i = 0; i < 8; ++i) {
        const long row = m0 + ty * 8 + i;
        alignas(16) float o[8];
        #pragma unroll
        for (int j = 0; j < 8; ++j) {
            float s = acc[i][j];
            if (RELU) s = fmaxf(s, 0.0f);
            o[j] = s;
        }
        *(float4*)&C[row * ldc + n0 + tx * 8]     = *(const float4*)&o[0];
        *(float4*)&C[row * ldc + n0 + tx * 8 + 4] = *(const float4*)&o[4];
    }
}

// ---------------------------------------------------------------------------
// Row softmax over 1024 elements, in place. One block (256 thr) per row.
// ---------------------------------------------------------------------------
__global__ __launch_bounds__(256) void softmax_kernel(float* __restrict__ P)
{
    const long row = blockIdx.x;
    float* p = P + row * 1024;
    const int t = threadIdx.x, lane = t & 63, wid = t >> 6;
    __shared__ float red[4];

    float4 v = ((float4*)p)[t];
    float m = fmaxf(fmaxf(v.x, v.y), fmaxf(v.z, v.w));
    #pragma unroll
    for (int o = 32; o; o >>= 1) m = fmaxf(m, __shfl_xor(m, o));
    if (lane == 0) red[wid] = m;
    __syncthreads();
    m = fmaxf(fmaxf(red[0], red[1]), fmaxf(red[2], red[3]));
    __syncthreads();

    float4 e;
    e.x = expf(v.x - m); e.y = expf(v.y - m);
    e.z = expf(v.z - m); e.w = expf(v.w - m);
    float s = e.x + e.y + e.z + e.w;
    #pragma unroll
    for (int o = 32; o; o >>= 1) s += __shfl_xor(s, o);
    if (lane == 0) red[wid] = s;
    __syncthreads();
    const float inv = 1.0f / (red[0] + red[1] + red[2] + red[3]);
    e.x *= inv; e.y *= inv; e.z *= inv; e.w *= inv;
    ((float4*)p)[t] = e;
}

// ---------------------------------------------------------------------------
// LayerNorm over 512 columns; one wave per row, 4 rows per block.
// ---------------------------------------------------------------------------
__global__ __launch_bounds__(256) void ln_kernel(const float* __restrict__ in,
                                                 const float* __restrict__ g,
                                                 const float* __restrict__ b,
                                                 float* __restrict__ out)
{
    const int wid = threadIdx.x >> 6, lane = threadIdx.x & 63;
    const long row = (long)blockIdx.x * 4 + wid;
    const float* p = in + row * D_MODEL;

    float4 v0 = ((const float4*)p)[lane];
    float4 v1 = ((const float4*)p)[64 + lane];
    float s = v0.x + v0.y + v0.z + v0.w + v1.x + v1.y + v1.z + v1.w;
    float q = v0.x*v0.x + v0.y*v0.y + v0.z*v0.z + v0.w*v0.w
            + v1.x*v1.x + v1.y*v1.y + v1.z*v1.z + v1.w*v1.w;
    #pragma unroll
    for (int o = 32; o; o >>= 1) { s += __shfl_xor(s, o); q += __shfl_xor(q, o); }

    const float mu  = s * (1.0f / D_MODEL);
    const float var = q * (1.0f / D_MODEL) - mu * mu;
    const float ri  = 1.0f / sqrtf(var + 1e-5f);

    float4 g0 = ((const float4*)g)[lane],      g1 = ((const float4*)g)[64 + lane];
    float4 b0 = ((const float4*)b)[lane],      b1 = ((const float4*)b)[64 + lane];
    float4 o0, o1;
    o0.x = (v0.x - mu) * ri * g0.x + b0.x; o0.y = (v0.y - mu) * ri * g0.y + b0.y;
    o0.z = (v0.z - mu) * ri * g0.z + b0.z; o0.w = (v0.w - mu) * ri * g0.w + b0.w;
    o1.x = (v1.x - mu) * ri * g1.x + b1.x; o1.y = (v1.y - mu) * ri * g1.y + b1.y;
    o1.z = (v1.z - mu) * ri * g1.z + b1.z; o1.w = (v1.w - mu) * ri * g1.w + b1.w;
    ((float4*)(out + row * D_MODEL))[lane]      = o0;
    ((float4*)(out + row * D_MODEL))[64 + lane] = o1;
}

// ---------------------------------------------------------------------------
extern "C" void kernel_launch(void* const* d_in, const int* in_sizes, int n_in,
                              void* d_out, int out_size, void* d_ws, size_t ws_size,
                              hipStream_t stream)
{
    (void)in_sizes; (void)n_in; (void)out_size; (void)ws_size;
    const int*   x   = (const int*)d_in[0];
    const float* emb = (const float*)d_in[1];
    const float* Wq  = (const float*)d_in[2];
    const float* Wk  = (const float*)d_in[3];
    const float* Wv  = (const float*)d_in[4];
    const float* Wo  = (const float*)d_in[5];
    const float* g1  = (const float*)d_in[6];
    const float* b1  = (const float*)d_in[7];
    const float* W1  = (const float*)d_in[8];
    const float* W2  = (const float*)d_in[9];
    const float* g2  = (const float*)d_in[10];
    const float* b2  = (const float*)d_in[11];

    float* out   = (float*)d_out;
    float* attns = out + H_ELEMS;
    float* ws    = (float*)d_ws;

    float* h   = ws;                       // 2M floats
    float* q   = ws + 2097152;             // 2M (aliased as ctx later)
    float* k   = ws + 4194304;             // 2M
    float* v   = ws + 6291456;             // 2M
    float* t2  = ws + 8388608;             // 2M
    float* t1  = ws + 10485760;            // 4M (FFN half-chunk 2048x2048)
    float* ctx = q;                        // q dead after scores

    embed_pe_kernel<<<TOKENS, 256, 0, stream>>>(x, emb, h);

    const dim3 g512(8, 64, 1);     // M=4096, N=512
    for (int l = 0; l < 6; ++l) {
        const float* wq = Wq + (long)l * 262144;
        const float* wk = Wk + (long)l * 262144;
        const float* wv = Wv + (long)l * 262144;
        const float* wo = Wo + (long)l * 262144;
        const float* w1 = W1 + (long)l * 1048576;
        const float* w2 = W2 + (long)l * 1048576;
        float* attn_l = attns + (long)l * ATTN_PER_LAYER;

        gemm64<0,false><<<g512,256,0,stream>>>(h, wq, nullptr, nullptr, q,
            4096,512,512, 512,512,512, 0,0,0,0,0,0, 0.f);
        gemm64<0,false><<<g512,256,0,stream>>>(h, wk, nullptr, nullptr, k,
            4096,512,512, 512,512,512, 0,0,0,0,0,0, 0.f);
        gemm64<0,false><<<g512,256,0,stream>>>(h, wv, nullptr, nullptr, v,
            4096,512,512, 512,512,512, 0,0,0,0,0,0, 0.f);

        // scores = Q @ K^T * scale, masked -> attns[l]
        dim3 gs(16, 16, 32);
        gemm64<2,true><<<gs,256,0,stream>>>(q, k, nullptr, x, attn_l,
            1024,1024,64, 512,512,1024,
            524288,64,  524288,64,  8388608,1048576, 0.125f);

        softmax_kernel<<<BATCHN*N_HEADS*SEQ, 256, 0, stream>>>(attn_l);

        // ctx = P @ V   (N=64 per head)
        dim3 gpv(1, 16, 32);
        gemm64<0,false><<<gpv,256,0,stream>>>(attn_l, v, nullptr, nullptr, ctx,
            1024,64,1024, 1024,512,512,
            8388608,1048576, 524288,64, 524288,64, 0.f);

        // t2 = ctx @ Wo + h ; h = LN(t2)
        gemm64<1,false><<<g512,256,0,stream>>>(ctx, wo, h, nullptr, t2,
            4096,512,512, 512,512,512, 0,0,0,0,0,0, 0.f);
        ln_kernel<<<1024,256,0,stream>>>(t2, g1 + l*512, b1 + l*512, h);

        // FFN in two 2048-row chunks (keeps ws small): t1 = relu(h@W1); t2 = t1@W2 + h
        for (int mc = 0; mc < 2; ++mc) {
            const float* hc = h + (long)mc * 2048 * 512;
            float* t2c = t2 + (long)mc * 2048 * 512;
            dim3 gf1(16, 16, 1);   // M=2048, N=2048
            gemm128<true><<<gf1,256,0,stream>>>(hc, w1, t1,
                2048,2048,512, 512,2048,2048);
            dim3 gf2(8, 32, 1);    // M=2048, N=512
            gemm64<1,false><<<gf2,256,0,stream>>>(t1, w2, hc, nullptr, t2c,
                2048,512,2048, 2048,512,512, 0,0,0,0,0,0, 0.f);
        }
        ln_kernel<<<1024,256,0,stream>>>(t2, g2 + l*512, b2 + l*512,
                                         (l == 5) ? out : h);
    }
}